// Round 4
// baseline (315.014 us; speedup 1.0000x reference)
//
#include <hip/hip_runtime.h>
#include <hip/hip_bf16.h>
#include <stdint.h>

#define NN 50000
#define EE 800000
#define DD 128
#define LL 3
#define NRANGE 8            // dst ranges (XCD-partition heuristic)
#define RSPAN (NN / NRANGE) // 6250 nodes per range
#define CAPA 256            // LDS stage slots per range per block (12 sigma of Binom(1024,1/8))
#define CAPSEG 104000       // global bucket capacity per range (13 sigma of Binom(800k,1/8))

typedef __attribute__((ext_vector_type(8))) short short8;
typedef __attribute__((ext_vector_type(4))) float float4v;

__device__ __forceinline__ float bf2f(unsigned int u) {
  union { unsigned int i; float f; } x; x.i = u << 16; return x.f;
}
__device__ __forceinline__ unsigned short f2bf(float f) {
  union { float f; unsigned int i; } x; x.f = f;
  unsigned int r = x.i + 0x7FFFu + ((x.i >> 16) & 1u);
  return (unsigned short)(r >> 16);
}

// ---------------- CSR build: phase A — bucket edges by dst range + degree histogram ----
// Reads src/dst ONCE (6.4 MB, coalesced int4). Ballot-compacts (src,dst) pairs into 8
// dst-range buckets via 16 KB LDS staging; one global cursor bump per (block,range).
// Replaces deg_kernel (deg atomics folded in) and kills fill's old 8x-redundant scans.
__global__ __launch_bounds__(256) void bucket_kernel(
    const int* __restrict__ src, const int* __restrict__ dst,
    int* __restrict__ deg, int* __restrict__ bcur, uint2* __restrict__ bkt, int E) {
  __shared__ int cnt[NRANGE];
  __shared__ int gbase[NRANGE];
  __shared__ uint2 stage[NRANGE][CAPA];
  const int tid = threadIdx.x;
  const int lane = tid & 63;
  if (tid < NRANGE) cnt[tid] = 0;
  __syncthreads();

  const int e0 = blockIdx.x * 1024 + tid * 4;
  int dv[4], sv[4];
  bool valid[4];
#pragma unroll
  for (int j = 0; j < 4; j++) valid[j] = (e0 + j) < E;
  if (e0 + 3 < E) {
    int4 d4 = *(const int4*)(dst + e0);
    int4 s4 = *(const int4*)(src + e0);
    dv[0] = d4.x; dv[1] = d4.y; dv[2] = d4.z; dv[3] = d4.w;
    sv[0] = s4.x; sv[1] = s4.y; sv[2] = s4.z; sv[3] = s4.w;
  } else {
#pragma unroll
    for (int j = 0; j < 4; j++) {
      dv[j] = valid[j] ? dst[e0 + j] : 0;
      sv[j] = valid[j] ? src[e0 + j] : 0;
    }
  }
  // degree histogram (fire-and-forget)
#pragma unroll
  for (int j = 0; j < 4; j++) if (valid[j]) atomicAdd(&deg[dv[j]], 1);

  const unsigned long long ltmask = (1ull << lane) - 1ull;
#pragma unroll
  for (int j = 0; j < 4; j++) {
    int r = valid[j] ? (dv[j] / RSPAN) : -1;
#pragma unroll
    for (int rr = 0; rr < NRANGE; rr++) {
      unsigned long long mask = __ballot(r == rr);
      if (mask == 0ull) continue;  // wave-uniform
      int leader = __ffsll((long long)mask) - 1;
      int base = 0;
      if (lane == leader) base = atomicAdd(&cnt[rr], (int)__popcll(mask));
      base = __shfl(base, leader, 64);
      if (r == rr) {
        int pos = base + (int)__popcll(mask & ltmask);
        uint2 pr; pr.x = (unsigned)sv[j]; pr.y = (unsigned)dv[j];
        if (pos < CAPA) {
          stage[rr][pos] = pr;
        } else {  // statistical-overflow spill (never taken for this input)
          int gpos = atomicAdd(&bcur[rr], 1);
          if (gpos < CAPSEG) bkt[(size_t)rr * CAPSEG + gpos] = pr;
        }
      }
    }
  }
  __syncthreads();
  if (tid < NRANGE) {
    int c = cnt[tid]; if (c > CAPA) c = CAPA;
    cnt[tid] = c;
    gbase[tid] = atomicAdd(&bcur[tid], c);
  }
  __syncthreads();
#pragma unroll
  for (int r = 0; r < NRANGE; r++) {
    int c = cnt[r], gb = gbase[r];
    for (int k = tid; k < c; k += 256) bkt[(size_t)r * CAPSEG + gb + k] = stage[r][k];
  }
}

// 3-phase parallel exclusive scan.
__global__ __launch_bounds__(256) void scan1_kernel(
    const int* __restrict__ deg, int* __restrict__ incl, int* __restrict__ partial, int N) {
  __shared__ int wsums[4];
  const int tid = threadIdx.x, lane = tid & 63, wid = tid >> 6;
  int i = blockIdx.x * 256 + tid;
  int v = (i < N) ? deg[i] : 0;
  int x = v;
#pragma unroll
  for (int off = 1; off < 64; off <<= 1) {
    int y = __shfl_up(x, off, 64);
    if (lane >= off) x += y;
  }
  if (lane == 63) wsums[wid] = x;
  __syncthreads();
  if (tid == 0) {
    int a0 = wsums[0], a1 = wsums[1], a2 = wsums[2];
    wsums[0] = 0; wsums[1] = a0; wsums[2] = a0 + a1; wsums[3] = a0 + a1 + a2;
  }
  __syncthreads();
  int inc = wsums[wid] + x;
  if (i < N) incl[i] = inc;
  if (tid == 255) partial[blockIdx.x] = inc;
}

__global__ __launch_bounds__(256) void scan2_kernel(int* __restrict__ partial, int P) {
  __shared__ int wsums[4];
  const int tid = threadIdx.x, lane = tid & 63, wid = tid >> 6;
  int v = (tid < P) ? partial[tid] : 0;
  int x = v;
#pragma unroll
  for (int off = 1; off < 64; off <<= 1) {
    int y = __shfl_up(x, off, 64);
    if (lane >= off) x += y;
  }
  if (lane == 63) wsums[wid] = x;
  __syncthreads();
  if (tid == 0) {
    int a0 = wsums[0], a1 = wsums[1], a2 = wsums[2];
    wsums[0] = 0; wsums[1] = a0; wsums[2] = a0 + a1; wsums[3] = a0 + a1 + a2;
  }
  __syncthreads();
  int excl = wsums[wid] + x - v;
  if (tid < P) partial[tid] = excl;
}

__global__ __launch_bounds__(256) void scan3_kernel(
    const int* __restrict__ incl, const int* __restrict__ deg, const int* __restrict__ partial,
    int* __restrict__ rowptr, int* __restrict__ cursor, int N) {
  int i = blockIdx.x * 256 + threadIdx.x;
  if (i < N) {
    int rp = incl[i] - deg[i] + partial[blockIdx.x];
    rowptr[i] = rp;
    cursor[i] = rp;
  }
  if (i == 0) rowptr[N] = EE;
}

// ---------------- CSR build: phase B — per-range scatter from compact buckets ----------
// blockIdx&7 = range (XCD round-robin heuristic): cursor atomics + col lines stay
// XCD-local. Reads its own bucket coalesced (uint2), no wasted scans.
__global__ __launch_bounds__(256) void fill2_kernel(
    const int* __restrict__ bcur, const uint2* __restrict__ bkt,
    int* __restrict__ cursor, int* __restrict__ col) {
  const int r = blockIdx.x & 7;
  const int chunk = blockIdx.x >> 3;
  const int nchunk = (int)(gridDim.x >> 3);
  int cnt = bcur[r];
  if (cnt > CAPSEG) cnt = CAPSEG;
  const int per = (cnt + nchunk - 1) / nchunk;
  const int i0 = chunk * per;
  int i1 = i0 + per; if (i1 > cnt) i1 = cnt;
  const uint2* seg = bkt + (size_t)r * CAPSEG;
  for (int ib = i0 + threadIdx.x * 4; ib < i1; ib += 256 * 4) {
    if (ib + 3 < i1) {
      uint2 p0 = seg[ib], p1 = seg[ib + 1], p2 = seg[ib + 2], p3 = seg[ib + 3];
      int q0 = atomicAdd(&cursor[p0.y], 1);
      int q1 = atomicAdd(&cursor[p1.y], 1);
      int q2 = atomicAdd(&cursor[p2.y], 1);
      int q3 = atomicAdd(&cursor[p3.y], 1);
      col[q0] = p0.x; col[q1] = p1.x; col[q2] = p2.x; col[q3] = p3.x;
    } else {
      for (int i = ib; i < i1; i++) {
        uint2 p = seg[i];
        int q = atomicAdd(&cursor[p.y], 1);
        col[q] = p.x;
      }
    }
  }
}

// ---------------- fp32 -> bf16 (x) ----------------
__global__ void convert_kernel(const float* __restrict__ x, unsigned short* __restrict__ hbf, int n4) {
  int i = blockIdx.x * blockDim.x + threadIdx.x;
  if (i < n4) {
    float4 v = ((const float4*)x)[i];
    ushort4 o;
    o.x = f2bf(v.x); o.y = f2bf(v.y); o.z = f2bf(v.z); o.w = f2bf(v.w);
    ((ushort4*)hbf)[i] = o;
  }
}

// ---------------- weight repack into MFMA B-fragment order (bf16) ----------------
// B[k][n]: k<128 -> Wl[l][n][k]; k>=128 -> Wr[l][n][k-128]
// layout [l][ks][t][lane][j]: n = t*16 + (lane&15), k = ks*32 + (lane>>4)*8 + j
__global__ void repack_kernel(const float* __restrict__ Wl, const float* __restrict__ Wr,
                              unsigned short* __restrict__ out) {
  int tid = blockIdx.x * blockDim.x + threadIdx.x;
  if (tid >= LL * 8 * 8 * 64) return;
  int lane = tid & 63;
  int t = (tid >> 6) & 7;
  int ks = (tid >> 9) & 7;
  int l = tid >> 12;
  int n = t * 16 + (lane & 15);
  int kbase = ks * 32 + (lane >> 4) * 8;
  const float* Wsrc = (ks < 4) ? (Wl + ((size_t)(l * 128 + n) * 128 + kbase))
                               : (Wr + ((size_t)(l * 128 + n) * 128 + (kbase - 128)));
#pragma unroll
  for (int j = 0; j < 8; j++) out[(size_t)tid * 8 + j] = f2bf(Wsrc[j]);
}

// ---------------- CSR pull mean-aggregation (bf16 gather, fp32 accum, bf16 out) ----------
// Paired-lane gather: lanes 0-31 even edges, 32-63 odd edges; uint2 (8 B) per lane.
// Round-1/2 data: same-bytes restructures are NULL -> agg is gather-BW-bound (~4.8 TB/s).
__global__ __launch_bounds__(256) void agg_kernel(
    const unsigned short* __restrict__ hbf, const int* __restrict__ rowptr,
    const int* __restrict__ col, unsigned short* __restrict__ agg, int N) {
  int node = blockIdx.x * 4 + (threadIdx.x >> 6);
  if (node >= N) return;
  int lane = threadIdx.x & 63;
  const int half = lane >> 5;   // 0: even edge of pair, 1: odd edge
  const int l32 = lane & 31;    // feature quad: features l32*4 .. l32*4+3
  int s = rowptr[node], e = rowptr[node + 1];
  float a0 = 0.f, a1 = 0.f, a2 = 0.f, a3 = 0.f;
  int i = s;
  // 8-pair (16-edge) main unroll
  for (; i + 15 < e; i += 16) {
    int idx[8];
#pragma unroll
    for (int j = 0; j < 8; j++) idx[j] = col[i + 2 * j + half];
    uint2 r[8];
#pragma unroll
    for (int j = 0; j < 8; j++) r[j] = ((const uint2*)(hbf + (size_t)idx[j] * 128))[l32];
#pragma unroll
    for (int j = 0; j < 8; j++) {
      a0 += bf2f(r[j].x & 0xffffu); a1 += bf2f(r[j].x >> 16);
      a2 += bf2f(r[j].y & 0xffffu); a3 += bf2f(r[j].y >> 16);
    }
  }
  if (i + 7 < e) {  // 4 pairs
    int idx[4];
#pragma unroll
    for (int j = 0; j < 4; j++) idx[j] = col[i + 2 * j + half];
    uint2 r[4];
#pragma unroll
    for (int j = 0; j < 4; j++) r[j] = ((const uint2*)(hbf + (size_t)idx[j] * 128))[l32];
#pragma unroll
    for (int j = 0; j < 4; j++) {
      a0 += bf2f(r[j].x & 0xffffu); a1 += bf2f(r[j].x >> 16);
      a2 += bf2f(r[j].y & 0xffffu); a3 += bf2f(r[j].y >> 16);
    }
    i += 8;
  }
  if (i + 3 < e) {  // 2 pairs
    int idx[2];
#pragma unroll
    for (int j = 0; j < 2; j++) idx[j] = col[i + 2 * j + half];
    uint2 r[2];
#pragma unroll
    for (int j = 0; j < 2; j++) r[j] = ((const uint2*)(hbf + (size_t)idx[j] * 128))[l32];
#pragma unroll
    for (int j = 0; j < 2; j++) {
      a0 += bf2f(r[j].x & 0xffffu); a1 += bf2f(r[j].x >> 16);
      a2 += bf2f(r[j].y & 0xffffu); a3 += bf2f(r[j].y >> 16);
    }
    i += 4;
  }
  if (i + 1 < e) {  // 1 pair
    int idx = col[i + half];
    uint2 r = ((const uint2*)(hbf + (size_t)idx * 128))[l32];
    a0 += bf2f(r.x & 0xffffu); a1 += bf2f(r.x >> 16);
    a2 += bf2f(r.y & 0xffffu); a3 += bf2f(r.y >> 16);
    i += 2;
  }
  if (i < e && half == 0) {  // final odd edge: half 0 only
    int idx = col[i];
    uint2 r = ((const uint2*)(hbf + (size_t)idx * 128))[l32];
    a0 += bf2f(r.x & 0xffffu); a1 += bf2f(r.x >> 16);
    a2 += bf2f(r.y & 0xffffu); a3 += bf2f(r.y >> 16);
  }
  // combine the two halves (lane ^ 32 holds the same feature columns, other edges)
  a0 += __shfl_xor(a0, 32);
  a1 += __shfl_xor(a1, 32);
  a2 += __shfl_xor(a2, 32);
  a3 += __shfl_xor(a3, 32);
  int dg = e - s;
  float inv = 1.0f / (float)(dg > 1 ? dg : 1);
  if (half == 0) {
    uint2 o;
    o.x = ((unsigned int)f2bf(a1 * inv) << 16) | (unsigned int)f2bf(a0 * inv);
    o.y = ((unsigned int)f2bf(a3 * inv) << 16) | (unsigned int)f2bf(a2 * inv);
    ((uint2*)(agg + (size_t)node * 128))[l32] = o;
  }
}

// ---------------- plain-bf16 MFMA GEMM + bias + LDS-epilogue LayerNorm + ReLU ----------------
// MFMA core + LDS-LN epilogue HW-validated (round-7 probe); plain-bf16 inputs validated
// round 10 (absmax 0.0234).
template <bool LAST>
__global__ __launch_bounds__(256) void gemm_ln_mfma_kernel(
    const unsigned short* __restrict__ agg, const unsigned short* __restrict__ h,
    const unsigned short* __restrict__ Bf, const float* __restrict__ bias,
    const float* __restrict__ gamma, const float* __restrict__ beta,
    unsigned short* __restrict__ out_bf, float* __restrict__ f_out, int N) {
  __shared__ unsigned short Bl[8 * 8 * 512];  // 64 KB
  __shared__ float reds[64][16];
  __shared__ float redss[64][16];
  __shared__ float mu_s[64], rs_s[64];
  const int tid = threadIdx.x;
  {
    const uint4* srcB = (const uint4*)Bf;
    uint4* dstB = (uint4*)Bl;
#pragma unroll
    for (int i = 0; i < 16; i++) dstB[tid + i * 256] = srcB[tid + i * 256];
  }
  __syncthreads();
  const int wave = tid >> 6, lane = tid & 63;
  const int ln16 = lane & 15, quad = lane >> 4;
  const int m0 = blockIdx.x * 64 + wave * 16;
  int row_a = m0 + ln16;
  if (row_a > N - 1) row_a = N - 1;  // clamp: MFMA rows independent; stores guarded below
  const size_t aoff = (size_t)row_a * 128 + quad * 8;

  float4v acc[8];
#pragma unroll
  for (int t = 0; t < 8; t++) acc[t] = (float4v)0.f;

#pragma unroll
  for (int ks = 0; ks < 8; ks++) {
    const unsigned short* ap = (ks < 4) ? (agg + aoff + ks * 32) : (h + aoff + (ks - 4) * 32);
    short8 a = *(const short8*)ap;
#pragma unroll
    for (int t = 0; t < 8; t++) {
      short8 b = *(const short8*)&Bl[(ks * 8 + t) * 512 + lane * 8];
      acc[t] = __builtin_amdgcn_mfma_f32_16x16x32_bf16(a, b, acc[t], 0, 0, 0);
    }
  }

  float bias_v[8], g_v[8], b_v[8];
#pragma unroll
  for (int t = 0; t < 8; t++) {
    int c = t * 16 + ln16;
    bias_v[t] = bias[c]; g_v[t] = gamma[c]; b_v[t] = beta[c];
  }
  // LDS-based LN statistics (no cross-lane shuffles — shfl-16 epilogue was the old bug)
#pragma unroll
  for (int r = 0; r < 4; r++) {
    float s = 0.f, ss = 0.f;
#pragma unroll
    for (int t = 0; t < 8; t++) {
      float val = acc[t][r] + bias_v[t];
      s += val; ss += val * val;
    }
    int rowblk = wave * 16 + quad * 4 + r;
    reds[rowblk][ln16] = s;
    redss[rowblk][ln16] = ss;
  }
  __syncthreads();
  if (tid < 64) {
    float s = 0.f, ss = 0.f;
#pragma unroll
    for (int g = 0; g < 16; g++) { s += reds[tid][g]; ss += redss[tid][g]; }
    float mu = s * (1.0f / 128.0f);
    float var = ss * (1.0f / 128.0f) - mu * mu;
    if (var < 0.f) var = 0.f;
    mu_s[tid] = mu;
    rs_s[tid] = rsqrtf(var + 1e-5f);
  }
  __syncthreads();
#pragma unroll
  for (int r = 0; r < 4; r++) {
    int row = m0 + quad * 4 + r;
    int rowblk = wave * 16 + quad * 4 + r;
    if (row < N) {
      float mu = mu_s[rowblk], rs = rs_s[rowblk];
#pragma unroll
      for (int t = 0; t < 8; t++) {
        float val = acc[t][r] + bias_v[t];
        float y = (val - mu) * rs * g_v[t] + b_v[t];
        y = y > 0.f ? y : 0.f;
        int cidx = t * 16 + ln16;
        if (LAST) {
          f_out[(size_t)row * 128 + cidx] = y;
        } else {
          out_bf[(size_t)row * 128 + cidx] = f2bf(y);
        }
      }
    }
  }
}

extern "C" void kernel_launch(void* const* d_in, const int* in_sizes, int n_in,
                              void* d_out, int out_size, void* d_ws, size_t ws_size,
                              hipStream_t stream) {
  const float* x = (const float*)d_in[0];
  const int* edge = (const int*)d_in[1];
  const float* Wl = (const float*)d_in[2];
  const float* bl = (const float*)d_in[3];
  const float* Wr = (const float*)d_in[4];
  const float* gamma = (const float*)d_in[5];
  const float* beta = (const float*)d_in[6];
  float* out = (float*)d_out;

  const int* srcv = edge;       // edge_index[0]
  const int* dstv = edge + EE;  // edge_index[1]

  char* p = (char*)d_ws;
  auto alloc = [&](size_t bytes) {
    char* r = p;
    p += (bytes + 255) & ~(size_t)255;
    return r;
  };
  const size_t bplane = (size_t)NN * 128 * 2;  // 12.8 MB bf16 plane
  unsigned short* xB = (unsigned short*)alloc(bplane);
  unsigned short* h1B = (unsigned short*)alloc(bplane);
  unsigned short* h2B = (unsigned short*)alloc(bplane);
  unsigned short* agB = (unsigned short*)alloc(bplane);
  unsigned short* BfB = (unsigned short*)alloc((size_t)LL * 32768 * 2);
  int* degzone = (int*)alloc((size_t)(NN + 64) * 4);  // deg[NN] + bcur[8] (one memset)
  int* deg = degzone;
  int* bcur = degzone + NN;
  int* incl = (int*)alloc((size_t)NN * 4);
  int* cursor = (int*)alloc((size_t)NN * 4);
  int* rowptr = (int*)alloc((size_t)(NN + 1) * 4);
  int* colarr = (int*)alloc((size_t)EE * 4);
  int* partial = (int*)alloc((size_t)256 * 4);
  uint2* bkt = (uint2*)alloc((size_t)NRANGE * CAPSEG * 8);  // 6.7 MB bucketed (src,dst)
  if ((size_t)(p - (char*)d_ws) > ws_size) return;

  const int SCAN_BLOCKS = (NN + 255) / 256;  // 196

  hipMemsetAsync(degzone, 0, (size_t)(NN + 64) * 4, stream);
  bucket_kernel<<<(EE + 1023) / 1024, 256, 0, stream>>>(srcv, dstv, deg, bcur, bkt, EE);
  scan1_kernel<<<SCAN_BLOCKS, 256, 0, stream>>>(deg, incl, partial, NN);
  scan2_kernel<<<1, 256, 0, stream>>>(partial, SCAN_BLOCKS);
  scan3_kernel<<<SCAN_BLOCKS, 256, 0, stream>>>(incl, deg, partial, rowptr, cursor, NN);
  fill2_kernel<<<8 * 98, 256, 0, stream>>>(bcur, bkt, cursor, colarr);
  convert_kernel<<<(NN * 128 / 4 + 255) / 256, 256, 0, stream>>>(x, xB, NN * 128 / 4);
  repack_kernel<<<(LL * 4096 + 255) / 256, 256, 0, stream>>>(Wl, Wr, BfB);

  const int gemm_grid = (NN + 63) / 64;
  const int agg_grid = (NN + 3) / 4;

  // ---- layer 0 ----
  agg_kernel<<<agg_grid, 256, 0, stream>>>(xB, rowptr, colarr, agB, NN);
  gemm_ln_mfma_kernel<false><<<gemm_grid, 256, 0, stream>>>(
      agB, xB, BfB, bl, gamma, beta, h1B, nullptr, NN);

  // ---- layer 1 ----
  agg_kernel<<<agg_grid, 256, 0, stream>>>(h1B, rowptr, colarr, agB, NN);
  gemm_ln_mfma_kernel<false><<<gemm_grid, 256, 0, stream>>>(
      agB, h1B, BfB + 32768, bl + 128, gamma + 128, beta + 128, h2B, nullptr, NN);

  // ---- layer 2 ----
  agg_kernel<<<agg_grid, 256, 0, stream>>>(h2B, rowptr, colarr, agB, NN);
  gemm_ln_mfma_kernel<true><<<gemm_grid, 256, 0, stream>>>(
      agB, h2B, BfB + 2 * 32768, bl + 256, gamma + 256, beta + 256, nullptr, out, NN);
}